// Round 1
// baseline (162.443 us; speedup 1.0000x reference)
//
#include <hip/hip_runtime.h>
#include <hip/hip_bf16.h>

#define NN 128
#define TT 256
#define EE 6
#define DD 10
#define TE (TT*EE)          // 1536
#define C1 15               // input1 inner dim: 1+E+E+2

// Kernel 0: w[j*TE + t*E + e] = 1 / input1[j,t,7+e]^2
__global__ void prep_w(const float* __restrict__ input1, float* __restrict__ w) {
    int idx = blockIdx.x * 256 + threadIdx.x;      // over N*T*E = 196608
    if (idx < NN * TE) {
        int f = idx % TE;
        int j = idx / TE;
        int t = f / EE, e = f % EE;
        float v = input1[(j * TT + t) * C1 + 1 + EE + e];
        w[idx] = 1.0f / (v * v);
    }
}

// Kernel 1: raw[i,j] = sum_{t,e} (yij[i,j,t,e]-yi[j,t,e])^2 * w[j,t,e]
// One 128-thread block per (i,j). 1536 floats = 384 float4 = 128 thr x 3.
__launch_bounds__(128)
__global__ void pair_reduce(const float* __restrict__ yij,
                            const float* __restrict__ yi,
                            const float* __restrict__ w,
                            float* __restrict__ raw) {
    const int j = blockIdx.x;
    const int i = blockIdx.y;
    const int tid = threadIdx.x;

    const float4* a  = (const float4*)(yij + ((size_t)i * NN + j) * TE);
    const float4* m  = (const float4*)(yi  + (size_t)j * TE);
    const float4* wv = (const float4*)(w   + (size_t)j * TE);

    float s = 0.0f;
#pragma unroll
    for (int k = 0; k < 3; ++k) {
        int f = tid + k * 128;
        float4 x  = a[f];
        float4 mm = m[f];
        float4 ww = wv[f];
        float d0 = x.x - mm.x; s += d0 * d0 * ww.x;
        float d1 = x.y - mm.y; s += d1 * d1 * ww.y;
        float d2 = x.z - mm.z; s += d2 * d2 * ww.z;
        float d3 = x.w - mm.w; s += d3 * d3 * ww.w;
    }
#pragma unroll
    for (int off = 32; off > 0; off >>= 1) s += __shfl_down(s, off);

    __shared__ float ls[2];
    if ((tid & 63) == 0) ls[tid >> 6] = s;
    __syncthreads();
    if (tid == 0) raw[i * NN + j] = ls[0] + ls[1];
}

// Kernel 2: L = mean_{i,j} | S_ij - 0.5*(sec[i,j]+sec[j,i]) |
// grid 64 x 256 threads; atomicAdd scaled partials into out[0] (pre-zeroed).
__launch_bounds__(256)
__global__ void finalize(const float* __restrict__ raw,
                         const float* __restrict__ samples,
                         float* __restrict__ out) {
    __shared__ float smp[NN * DD];     // 1280 floats
    for (int k = threadIdx.x; k < NN * DD; k += 256) smp[k] = samples[k];
    __syncthreads();

    const int p = blockIdx.x * 256 + threadIdx.x;   // 0..16383
    const int i = p / NN, j = p % NN;

    float S = 0.0f;
#pragma unroll
    for (int d = 0; d < DD; ++d) {
        float dd = smp[j * DD + d] - smp[i * DD + d];
        S += dd * dd;
    }
    S *= (1.0f / DD);

    const float sec = (raw[i * NN + j] + raw[j * NN + i]) * (0.5f / (TE * 10.0f));
    float v = fabsf(S - sec);

#pragma unroll
    for (int off = 32; off > 0; off >>= 1) v += __shfl_down(v, off);

    __shared__ float ls[4];
    const int tid = threadIdx.x;
    if ((tid & 63) == 0) ls[tid >> 6] = v;
    __syncthreads();
    if (tid == 0)
        atomicAdd(out, (ls[0] + ls[1] + ls[2] + ls[3]) * (1.0f / (NN * NN)));
}

extern "C" void kernel_launch(void* const* d_in, const int* in_sizes, int n_in,
                              void* d_out, int out_size, void* d_ws, size_t ws_size,
                              hipStream_t stream) {
    // inputs (setup_inputs order): merged, y_pred_i, y_pred_ij, input1, samples, labels
    const float* y_pred_i  = (const float*)d_in[1];
    const float* y_pred_ij = (const float*)d_in[2];
    const float* input1    = (const float*)d_in[3];
    const float* samples   = (const float*)d_in[4];
    float* out = (float*)d_out;

    // workspace layout: w (N*TE floats) | raw (N*N floats)
    float* w   = (float*)d_ws;
    float* raw = w + (size_t)NN * TE;

    prep_w<<<(NN * TE + 255) / 256, 256, 0, stream>>>(input1, w);

    dim3 grid(NN, NN);
    pair_reduce<<<grid, 128, 0, stream>>>(y_pred_ij, y_pred_i, w, raw);

    hipMemsetAsync(out, 0, sizeof(float), stream);
    finalize<<<64, 256, 0, stream>>>(raw, samples, out);
}